// Round 3
// baseline (161.307 us; speedup 1.0000x reference)
//
#include <hip/hip_runtime.h>
#include <math.h>

#define NB_B 4
#define NB_N 8
#define NB_C 256
#define NB_K 16
#define NB_P 4096
#define NB_BN (NB_B * NB_N)

// workspace float offsets
#define WS_WSUM 0
#define WS_VSUM (NB_BN * NB_C)                    // 8192
#define WS_GT   (2 * NB_BN * NB_C)                // 16384
#define WS_DEN  (WS_GT + NB_B * NB_C)             // 17408
#define WS_NB   17440                             // normalized bank, [bn][c][k]
#define WS_PN   (WS_NB + NB_BN * NB_K * NB_C)     // 148512: proto_new, [bn][c][k]
#define WS_VAL  (WS_PN + NB_BN * NB_K * NB_C)     // 279584

// ---------------- reduction helpers ----------------
// 8-value batched block reduction (blockDim 256, 4 waves)
__device__ __forceinline__ void blk_sum8(float* a, float (*sbuf)[8]) {
#pragma unroll
  for (int off = 32; off > 0; off >>= 1) {
#pragma unroll
    for (int j = 0; j < 8; ++j) a[j] += __shfl_down(a[j], off, 64);
  }
  int lane = threadIdx.x & 63, wid = threadIdx.x >> 6;
  __syncthreads();
  if (lane == 0) {
#pragma unroll
    for (int j = 0; j < 8; ++j) sbuf[wid][j] = a[j];
  }
  __syncthreads();
#pragma unroll
  for (int j = 0; j < 8; ++j)
    a[j] = sbuf[0][j] + sbuf[1][j] + sbuf[2][j] + sbuf[3][j];
}

__device__ __forceinline__ float2 blk_sum2(float a, float b, float2* sbuf) {
#pragma unroll
  for (int off = 32; off > 0; off >>= 1) {
    a += __shfl_down(a, off, 64);
    b += __shfl_down(b, off, 64);
  }
  int lane = threadIdx.x & 63, wid = threadIdx.x >> 6;
  __syncthreads();
  if (lane == 0) sbuf[wid] = make_float2(a, b);
  __syncthreads();
  float2 r;
  r.x = sbuf[0].x + sbuf[1].x + sbuf[2].x + sbuf[3].x;
  r.y = sbuf[0].y + sbuf[1].y + sbuf[2].y + sbuf[3].y;
  return r;
}

__device__ __forceinline__ float2 blk_max2(float a, float b, float2* sbuf) {
#pragma unroll
  for (int off = 32; off > 0; off >>= 1) {
    a = fmaxf(a, __shfl_down(a, off, 64));
    b = fmaxf(b, __shfl_down(b, off, 64));
  }
  int lane = threadIdx.x & 63, wid = threadIdx.x >> 6;
  __syncthreads();
  if (lane == 0) sbuf[wid] = make_float2(a, b);
  __syncthreads();
  float2 r;
  r.x = fmaxf(fmaxf(sbuf[0].x, sbuf[1].x), fmaxf(sbuf[2].x, sbuf[3].x));
  r.y = fmaxf(fmaxf(sbuf[0].y, sbuf[1].y), fmaxf(sbuf[2].y, sbuf[3].y));
  return r;
}

// ---------------- robust decoding of the bool `valid` input ----------------
__device__ __forceinline__ int validMode(const void* vptr) {
  const unsigned int* w = (const unsigned int*)vptr;
  int mode = 0;  // 0 = int32
  for (int i = 0; i < 128; ++i) {
    unsigned int x = w[i];
    if (x == 0x3f800000u) return 2;      // float32 1.0 present -> f32
    if (x > 1u) mode = 1;                // packed bytes -> uint8
  }
  return mode;
}
__device__ __forceinline__ bool getValid(const void* vptr, int mode, int idx) {
  if (mode == 1) return ((const unsigned char*)vptr)[idx] != 0;
  if (mode == 2) return ((const float*)vptr)[idx] != 0.0f;
  return ((const int*)vptr)[idx] != 0;
}

// ---------------- kernel 1: big reductions over P (4 rows per block) ----------------
__global__ __launch_bounds__(256) void k1_reduce(
    const float* __restrict__ value, const float* __restrict__ frame,
    const float* __restrict__ mask, float* __restrict__ ws) {
  __shared__ float sbuf[4][8];
  int gid = blockIdx.x, tid = threadIdx.x;
  if (gid < 2048) {
    // 4 value rows (same bn) pooled against one mask row
    int bn = gid >> 6, c0 = (gid & 63) << 2;
    const float4* m4 = (const float4*)(mask + (size_t)bn * NB_P);
    float4 mv[4];
#pragma unroll
    for (int i = 0; i < 4; ++i) mv[i] = m4[i * 256 + tid];
    float acc[8];
#pragma unroll
    for (int r = 0; r < 4; ++r) {
      const float4* v4 =
          (const float4*)(value + ((size_t)bn * NB_C + c0 + r) * NB_P);
      float wsum = 0.f, vsum = 0.f;
#pragma unroll
      for (int i = 0; i < 4; ++i) {
        float4 a = v4[i * 256 + tid];
        wsum += a.x * mv[i].x + a.y * mv[i].y + a.z * mv[i].z + a.w * mv[i].w;
        vsum += a.x + a.y + a.z + a.w;
      }
      acc[2 * r] = wsum;
      acc[2 * r + 1] = vsum;
    }
    blk_sum8(acc, sbuf);
    if (tid == 0) {
#pragma unroll
      for (int r = 0; r < 4; ++r) {
        ws[WS_WSUM + bn * NB_C + c0 + r] = acc[2 * r];
        ws[WS_VSUM + bn * NB_C + c0 + r] = acc[2 * r + 1];
      }
    }
  } else if (gid < 2048 + 256) {
    // 4 frame rows -> g_t means
    int idx0 = (gid - 2048) << 2;
    float acc[8] = {0.f, 0.f, 0.f, 0.f, 0.f, 0.f, 0.f, 0.f};
#pragma unroll
    for (int r = 0; r < 4; ++r) {
      const float4* f4 = (const float4*)(frame + (size_t)(idx0 + r) * NB_P);
      float s = 0.f;
#pragma unroll
      for (int i = 0; i < 4; ++i) {
        float4 a = f4[i * 256 + tid];
        s += a.x + a.y + a.z + a.w;
      }
      acc[r] = s;
    }
    blk_sum8(acc, sbuf);
    if (tid == 0) {
#pragma unroll
      for (int r = 0; r < 4; ++r)
        ws[WS_GT + idx0 + r] = acc[r] * (1.0f / NB_P);
    }
  } else {
    // mask denom per bn
    int bn = gid - 2304;
    const float4* m4 = (const float4*)(mask + (size_t)bn * NB_P);
    float acc[8] = {0.f, 0.f, 0.f, 0.f, 0.f, 0.f, 0.f, 0.f};
    float s = 0.f;
#pragma unroll
    for (int i = 0; i < 4; ++i) {
      float4 a = m4[i * 256 + tid];
      s += a.x + a.y + a.z + a.w;
    }
    acc[0] = s;
    blk_sum8(acc, sbuf);
    if (tid == 0) ws[WS_DEN + bn] = acc[0];
  }
}

// ---------------- kernel 2: per-(b,n) policy + bank update ----------------
__global__ __launch_bounds__(256) void k2_policy(
    const float* __restrict__ proto, const float* __restrict__ age,
    const float* __restrict__ usage, const float* __restrict__ conf,
    const void* __restrict__ valid, const float* __restrict__ W1,
    const float* __restrict__ b1, const float* __restrict__ W2,
    const float* __restrict__ b2, float* __restrict__ ws,
    float* __restrict__ out_logits) {
  __shared__ float2 sbuf[4];
  __shared__ float s_cand[NB_C];
  __shared__ float s_sim[NB_K];
  __shared__ float s_invn[NB_K];
  __shared__ float s_ctx[NB_C + NB_K + 3 * NB_K];  // 320
  __shared__ int s_dec[4];

  int bn = blockIdx.x;
  int b = bn >> 3;
  int c = threadIdx.x;
  int vmode = validMode(valid);

  float denom = ws[WS_DEN + bn];
  float cand;
  if (denom <= 1e-5f) cand = ws[WS_VSUM + bn * NB_C + c] * (1.0f / NB_P);
  else                cand = ws[WS_WSUM + bn * NB_C + c] / fmaxf(denom, 1e-6f);
  float2 r0 = blk_sum2(cand * cand, 0.f, sbuf);
  cand *= 1.0f / fmaxf(sqrtf(r0.x), 1e-12f);
  s_cand[c] = cand;

  const float* pr = proto + (size_t)bn * NB_K * NB_C;
  for (int k = 0; k < NB_K; ++k) {
    float p = pr[k * NB_C + c];
    float2 rr = blk_sum2(p * p, p * cand, sbuf);
    if (c == 0) {
      float invk = 1.0f / fmaxf(sqrtf(rr.x), 1e-12f);
      s_invn[k] = invk;
      s_sim[k] = getValid(valid, vmode, bn * NB_K + k) ? rr.y * invk : -1.0f;
    }
  }

  float am = fmaxf(age[c], age[c + 256]);
  float um = fmaxf(usage[c], usage[c + 256]);
  float2 mx = blk_max2(am, um, sbuf);
  float age_max = fmaxf(mx.x, 1.0f);
  float use_max = fmaxf(mx.y, 1.0f);

  s_ctx[c] = ws[WS_GT + b * NB_C + c];
  if (c < NB_K) {
    int k = c;
    s_ctx[NB_C + k] = s_sim[k];
    s_ctx[NB_C + NB_K + 3 * k + 0] = age[bn * NB_K + k] / age_max;
    s_ctx[NB_C + NB_K + 3 * k + 1] = usage[bn * NB_K + k] / use_max;
    s_ctx[NB_C + NB_K + 3 * k + 2] = conf[bn * NB_K + k];
  }
  __syncthreads();

  float acc = b1[c];
  for (int i = 0; i < NB_C + 4 * NB_K; ++i) acc += s_ctx[i] * W1[i * 256 + c];
  float h = 0.5f * acc *
            (1.0f + tanhf(0.7978845608028654f * (acc + 0.044715f * acc * acc * acc)));
  for (int j = 0; j < 4; ++j) {
    float2 lj = blk_sum2(h * W2[c * 4 + j], 0.f, sbuf);
    if (c == 0) out_logits[bn * 4 + j] = lj.x + b2[j];
  }

  if (c == 0) {
    bool anyv = false, hasfree = false;
    for (int k = 0; k < NB_K; ++k) {
      if (getValid(valid, vmode, bn * NB_K + k)) anyv = true; else hasfree = true;
    }
    int tgt = 0; float best = s_sim[0];
    for (int k = 1; k < NB_K; ++k) if (s_sim[k] > best) { best = s_sim[k]; tgt = k; }
    if (!anyv) tgt = 0;
    float max_sim = anyv ? s_sim[tgt] : 0.0f;
    int action = 1;                       // REFINE
    if (max_sim > 0.85f) action = 0;      // KEEP
    bool low = max_sim < 0.5f;
    if (low && hasfree) action = 3;       // SPAWN
    if (low && !hasfree) action = 2;      // REPLACE
    int worst = 0; float wb = -1e30f;
    for (int k = 0; k < NB_K; ++k) {
      float sc = age[bn * NB_K + k] - usage[bn * NB_K + k] - conf[bn * NB_K + k] +
                 (getValid(valid, vmode, bn * NB_K + k) ? 0.f : 1000.f);
      if (sc > wb) { wb = sc; worst = k; }
    }
    int freeslot = 0;
    for (int k = 0; k < NB_K; ++k) {
      if (!getValid(valid, vmode, bn * NB_K + k)) { freeslot = k; break; }
    }
    int chosen = tgt;
    if (action == 3) chosen = hasfree ? freeslot : worst;
    if (action == 2) chosen = worst;
    s_dec[0] = chosen;
    s_dec[1] = (action == 1);
    s_dec[2] = (action == 2 || action == 3);
    s_dec[3] = (action != 0);
  }
  __syncthreads();

  // proto_new (unnormalized) + normalized bank -> workspace, layout [c][k]
  int chosen = s_dec[0];
  float oldp = pr[chosen * NB_C + c];
  float t = 0.9f * oldp + 0.1f * s_cand[c];
  float2 tn = blk_sum2(t * t, 0.f, sbuf);
  float invt = 1.0f / fmaxf(sqrtf(tn.x), 1e-12f);
  float pn_chosen = s_dec[1] ? t * invt
                   : (s_dec[2] ? s_cand[c] : oldp);
  float nb_chosen = s_dec[1] ? t * invt
                   : (s_dec[2] ? s_cand[c] : oldp * s_invn[chosen]);
  float* nbp = ws + WS_NB + (size_t)bn * NB_K * NB_C;
  float* pnp = ws + WS_PN + (size_t)bn * NB_K * NB_C;
  for (int k = 0; k < NB_K; ++k) {
    float praw = pr[k * NB_C + c];
    nbp[c * NB_K + k] = (k == chosen) ? nb_chosen : praw * s_invn[k];
    pnp[c * NB_K + k] = (k == chosen) ? pn_chosen : praw;
  }
  if (c < NB_K) {
    bool v = getValid(valid, vmode, bn * NB_K + c) || (c == chosen && s_dec[3]);
    ws[WS_VAL + bn * NB_K + c] = v ? 1.0f : 0.0f;
  }
}

// ---------------- kernel 3: prototype-conditioned readout ----------------
// 128 px/block, C split across two thread-halves; grid = 32 bn x 32 tiles = 1024
__global__ __launch_bounds__(256, 4) void k3_readout(
    const float* __restrict__ value, const float* __restrict__ frame,
    const float* __restrict__ ws, const float* __restrict__ pgp,
    const float* __restrict__ fgp, float* __restrict__ out) {
  __shared__ float s_bank[NB_C * NB_K];   // 16 KB: nb in pass 1, pn in pass 2
  __shared__ float s_red[256 * 17];       // 17 KB partials (stride 17: conflict-free)
  int blk = blockIdx.x;
  int bn = blk >> 5, tile = blk & 31;
  int b = bn >> 3;
  int tid = threadIdx.x;
  int px = tid & 127, ch = tid >> 7;
  int p0 = tile * 128;

  // stage normalized bank ([c][k] in ws -> same layout in LDS, float4 both sides)
  const float4* nbp4 = (const float4*)(ws + WS_NB + (size_t)bn * NB_K * NB_C);
  float4* sb4 = (float4*)s_bank;
#pragma unroll
  for (int j = 0; j < 4; ++j) sb4[j * 256 + tid] = nbp4[j * 256 + tid];
  int vmask = 0;
  for (int k = 0; k < NB_K; ++k)
    if (ws[WS_VAL + bn * NB_K + k] != 0.0f) vmask |= (1 << k);
  float pg = pgp[0], fg = fgp[0];
  __syncthreads();

  // pass 1: partial dots over this thread's 128-channel half
  const float* vp = value + ((size_t)bn * NB_C + ch * 128) * NB_P + p0 + px;
  const float* sbch = s_bank + ch * 128 * NB_K;
  float d[NB_K];
#pragma unroll
  for (int k = 0; k < NB_K; ++k) d[k] = 0.f;
  float sumsq = 0.f;
#pragma unroll 8
  for (int c = 0; c < 128; ++c) {
    float v = vp[(size_t)c * NB_P];
    sumsq += v * v;
    const float4* n4 = (const float4*)(sbch + c * NB_K);
    float4 n0 = n4[0], n1 = n4[1], n2 = n4[2], n3 = n4[3];
    d[0] += v * n0.x;  d[1] += v * n0.y;  d[2] += v * n0.z;  d[3] += v * n0.w;
    d[4] += v * n1.x;  d[5] += v * n1.y;  d[6] += v * n1.z;  d[7] += v * n1.w;
    d[8] += v * n2.x;  d[9] += v * n2.y;  d[10] += v * n2.z; d[11] += v * n2.w;
    d[12] += v * n3.x; d[13] += v * n3.y; d[14] += v * n3.z; d[15] += v * n3.w;
  }
  {
    float* rr = s_red + tid * 17;
#pragma unroll
    for (int k = 0; k < NB_K; ++k) rr[k] = d[k];
    rr[16] = sumsq;
  }
  __syncthreads();  // pass-1 LDS reads done; s_bank free, s_red complete

  // restage proto_new into s_bank (overlap with reduction below)
  const float4* pnp4 = (const float4*)(ws + WS_PN + (size_t)bn * NB_K * NB_C);
#pragma unroll
  for (int j = 0; j < 4; ++j) sb4[j * 256 + tid] = pnp4[j * 256 + tid];

  // combine halves + softmax (both c-halves compute their pixel's weights)
  {
    const float* r0 = s_red + px * 17;
    const float* r1 = s_red + (128 + px) * 17;
#pragma unroll
    for (int k = 0; k < NB_K; ++k) d[k] = r0[k] + r1[k];
    sumsq = r0[16] + r1[16];
  }
  float invv = 1.0f / fmaxf(sqrtf(sumsq), 1e-12f);
  float m = -1e30f;
#pragma unroll
  for (int k = 0; k < NB_K; ++k) {
    d[k] *= invv;
    if ((vmask >> k) & 1) m = fmaxf(m, d[k]);
  }
  float w[NB_K]; float ssum = 0.f;
#pragma unroll
  for (int k = 0; k < NB_K; ++k) {
    float e = ((vmask >> k) & 1) ? __expf(d[k] - m) : 0.f;
    w[k] = e; ssum += e;
  }
  float isum = vmask ? (1.0f / ssum) : 0.0f;
#pragma unroll
  for (int k = 0; k < NB_K; ++k) w[k] *= isum;
  __syncthreads();  // s_bank now holds proto_new

  // pass 2: output for this thread's 128-channel half (nt stores keep value in L3)
  const float* fp = frame + ((size_t)b * NB_C + ch * 128) * NB_P + p0 + px;
  float* op = out + ((size_t)bn * NB_C + ch * 128) * NB_P + p0 + px;
#pragma unroll 4
  for (int c = 0; c < 128; ++c) {
    float v = vp[(size_t)c * NB_P];
    float f = fp[(size_t)c * NB_P];
    const float4* n4 = (const float4*)(sbch + c * NB_K);
    float4 n0 = n4[0], n1 = n4[1], n2 = n4[2], n3 = n4[3];
    float pm = w[0] * n0.x + w[1] * n0.y + w[2] * n0.z + w[3] * n0.w +
               w[4] * n1.x + w[5] * n1.y + w[6] * n1.z + w[7] * n1.w +
               w[8] * n2.x + w[9] * n2.y + w[10] * n2.z + w[11] * n2.w +
               w[12] * n3.x + w[13] * n3.y + w[14] * n3.z + w[15] * n3.w;
    __builtin_nontemporal_store(v + pg * pm + fg * f, &op[(size_t)c * NB_P]);
  }
}

extern "C" void kernel_launch(void* const* d_in, const int* in_sizes, int n_in,
                              void* d_out, int out_size, void* d_ws, size_t ws_size,
                              hipStream_t stream) {
  const float* value = (const float*)d_in[0];
  const float* frame = (const float*)d_in[1];
  const float* mask  = (const float*)d_in[2];
  const float* proto = (const float*)d_in[3];
  const float* age   = (const float*)d_in[4];
  const float* usage = (const float*)d_in[5];
  const float* conf  = (const float*)d_in[6];
  const void*  valid = (const void*)d_in[7];
  const float* W1 = (const float*)d_in[8];
  const float* b1 = (const float*)d_in[9];
  const float* W2 = (const float*)d_in[10];
  const float* b2 = (const float*)d_in[11];
  const float* pg = (const float*)d_in[12];
  const float* fg = (const float*)d_in[13];
  float* out = (float*)d_out;
  float* ws = (float*)d_ws;

  hipLaunchKernelGGL(k1_reduce, dim3(2048 + 256 + 32), dim3(256), 0, stream,
                     value, frame, mask, ws);
  hipLaunchKernelGGL(k2_policy, dim3(NB_BN), dim3(256), 0, stream,
                     proto, age, usage, conf, valid, W1, b1, W2, b2, ws,
                     out + (size_t)NB_BN * NB_C * NB_P);
  hipLaunchKernelGGL(k3_readout, dim3(NB_BN * 32), dim3(256), 0, stream,
                     value, frame, ws, pg, fg, out);
}

// Round 5
// 147.969 us; speedup vs baseline: 1.0901x; 1.0901x over previous
//
#include <hip/hip_runtime.h>
#include <math.h>

#define NB_B 4
#define NB_N 8
#define NB_C 256
#define NB_K 16
#define NB_P 4096
#define NB_BN (NB_B * NB_N)
#define NB_GP (NB_BN * NB_P)                      // 131072 global pixels

typedef float nfloat4 __attribute__((ext_vector_type(4)));  // NT-store-able

// workspace float offsets
#define WS_WSUM 0
#define WS_VSUM (NB_BN * NB_C)                    // 8192
#define WS_GT   (2 * NB_BN * NB_C)                // 16384
#define WS_DEN  (WS_GT + NB_B * NB_C)             // 17408
#define WS_NB   17440                             // normalized bank, [bn][c][k]
#define WS_PN   (WS_NB + NB_BN * NB_K * NB_C)     // 148512: proto_new, [bn][c][k]
#define WS_VAL  (WS_PN + NB_BN * NB_K * NB_C)     // 279584
#define WS_W    280096                            // softmax wts, [k 16][gpx]
#define WS_PART (WS_W + NB_K * NB_GP)             // partials, [slab 4][17][gpx]
#define WS_END  (WS_PART + 4 * 17 * NB_GP)        // 11,290,144 floats

// ---------------- block reduction helpers (blockDim == 256, 4 waves) ----------------
__device__ __forceinline__ float2 blk_sum2(float a, float b, float2* sbuf) {
#pragma unroll
  for (int off = 32; off > 0; off >>= 1) {
    a += __shfl_down(a, off, 64);
    b += __shfl_down(b, off, 64);
  }
  int lane = threadIdx.x & 63, wid = threadIdx.x >> 6;
  __syncthreads();
  if (lane == 0) sbuf[wid] = make_float2(a, b);
  __syncthreads();
  float2 r;
  r.x = sbuf[0].x + sbuf[1].x + sbuf[2].x + sbuf[3].x;
  r.y = sbuf[0].y + sbuf[1].y + sbuf[2].y + sbuf[3].y;
  return r;
}

__device__ __forceinline__ float2 blk_max2(float a, float b, float2* sbuf) {
#pragma unroll
  for (int off = 32; off > 0; off >>= 1) {
    a = fmaxf(a, __shfl_down(a, off, 64));
    b = fmaxf(b, __shfl_down(b, off, 64));
  }
  int lane = threadIdx.x & 63, wid = threadIdx.x >> 6;
  __syncthreads();
  if (lane == 0) sbuf[wid] = make_float2(a, b);
  __syncthreads();
  float2 r;
  r.x = fmaxf(fmaxf(sbuf[0].x, sbuf[1].x), fmaxf(sbuf[2].x, sbuf[3].x));
  r.y = fmaxf(fmaxf(sbuf[0].y, sbuf[1].y), fmaxf(sbuf[2].y, sbuf[3].y));
  return r;
}

// ---------------- robust decoding of the bool `valid` input ----------------
__device__ __forceinline__ int validMode(const void* vptr) {
  const unsigned int* w = (const unsigned int*)vptr;
  int mode = 0;  // 0 = int32
  for (int i = 0; i < 128; ++i) {
    unsigned int x = w[i];
    if (x == 0x3f800000u) return 2;      // float32 1.0 present -> f32
    if (x > 1u) mode = 1;                // packed bytes -> uint8
  }
  return mode;
}
__device__ __forceinline__ bool getValid(const void* vptr, int mode, int idx) {
  if (mode == 1) return ((const unsigned char*)vptr)[idx] != 0;
  if (mode == 2) return ((const float*)vptr)[idx] != 0.0f;
  return ((const int*)vptr)[idx] != 0;
}

// ---------------- kernel 1: big reductions over P (round-2 form) ----------------
__global__ __launch_bounds__(256) void k1_reduce(
    const float* __restrict__ value, const float* __restrict__ frame,
    const float* __restrict__ mask, float* __restrict__ ws) {
  __shared__ float2 sbuf[4];
  int gid = blockIdx.x, tid = threadIdx.x;
  if (gid < NB_BN * NB_C) {
    int bn = gid >> 8;
    const float4* v4 = (const float4*)(value + (size_t)gid * NB_P);
    const float4* m4 = (const float4*)(mask + (size_t)bn * NB_P);
    float wsum = 0.f, vsum = 0.f;
#pragma unroll
    for (int i = 0; i < NB_P / 4 / 256; ++i) {
      float4 a = v4[i * 256 + tid];
      float4 m = m4[i * 256 + tid];
      wsum += a.x * m.x + a.y * m.y + a.z * m.z + a.w * m.w;
      vsum += a.x + a.y + a.z + a.w;
    }
    float2 r = blk_sum2(wsum, vsum, sbuf);
    if (tid == 0) { ws[WS_WSUM + gid] = r.x; ws[WS_VSUM + gid] = r.y; }
  } else if (gid < NB_BN * NB_C + NB_B * NB_C) {
    int idx = gid - NB_BN * NB_C;
    const float4* f4 = (const float4*)(frame + (size_t)idx * NB_P);
    float s = 0.f;
#pragma unroll
    for (int i = 0; i < 4; ++i) {
      float4 a = f4[i * 256 + tid];
      s += a.x + a.y + a.z + a.w;
    }
    float2 r = blk_sum2(s, 0.f, sbuf);
    if (tid == 0) ws[WS_GT + idx] = r.x * (1.0f / NB_P);
  } else {
    int bn = gid - NB_BN * NB_C - NB_B * NB_C;
    const float4* m4 = (const float4*)(mask + (size_t)bn * NB_P);
    float s = 0.f;
#pragma unroll
    for (int i = 0; i < 4; ++i) {
      float4 a = m4[i * 256 + tid];
      s += a.x + a.y + a.z + a.w;
    }
    float2 r = blk_sum2(s, 0.f, sbuf);
    if (tid == 0) ws[WS_DEN + bn] = r.x;
  }
}

// ---------------- kernel 2: per-(b,n) policy + bank update ----------------
__global__ __launch_bounds__(256) void k2_policy(
    const float* __restrict__ proto, const float* __restrict__ age,
    const float* __restrict__ usage, const float* __restrict__ conf,
    const void* __restrict__ valid, const float* __restrict__ W1,
    const float* __restrict__ b1, const float* __restrict__ W2,
    const float* __restrict__ b2, float* __restrict__ ws,
    float* __restrict__ out_logits) {
  __shared__ float2 sbuf[4];
  __shared__ float s_cand[NB_C];
  __shared__ float s_sim[NB_K];
  __shared__ float s_invn[NB_K];
  __shared__ float s_ctx[NB_C + NB_K + 3 * NB_K];  // 320
  __shared__ int s_dec[4];

  int bn = blockIdx.x;
  int b = bn >> 3;
  int c = threadIdx.x;
  int vmode = validMode(valid);

  float denom = ws[WS_DEN + bn];
  float cand;
  if (denom <= 1e-5f) cand = ws[WS_VSUM + bn * NB_C + c] * (1.0f / NB_P);
  else                cand = ws[WS_WSUM + bn * NB_C + c] / fmaxf(denom, 1e-6f);
  float2 r0 = blk_sum2(cand * cand, 0.f, sbuf);
  cand *= 1.0f / fmaxf(sqrtf(r0.x), 1e-12f);
  s_cand[c] = cand;

  const float* pr = proto + (size_t)bn * NB_K * NB_C;
  for (int k = 0; k < NB_K; ++k) {
    float p = pr[k * NB_C + c];
    float2 rr = blk_sum2(p * p, p * cand, sbuf);
    if (c == 0) {
      float invk = 1.0f / fmaxf(sqrtf(rr.x), 1e-12f);
      s_invn[k] = invk;
      s_sim[k] = getValid(valid, vmode, bn * NB_K + k) ? rr.y * invk : -1.0f;
    }
  }

  float am = fmaxf(age[c], age[c + 256]);
  float um = fmaxf(usage[c], usage[c + 256]);
  float2 mx = blk_max2(am, um, sbuf);
  float age_max = fmaxf(mx.x, 1.0f);
  float use_max = fmaxf(mx.y, 1.0f);

  s_ctx[c] = ws[WS_GT + b * NB_C + c];
  if (c < NB_K) {
    int k = c;
    s_ctx[NB_C + k] = s_sim[k];
    s_ctx[NB_C + NB_K + 3 * k + 0] = age[bn * NB_K + k] / age_max;
    s_ctx[NB_C + NB_K + 3 * k + 1] = usage[bn * NB_K + k] / use_max;
    s_ctx[NB_C + NB_K + 3 * k + 2] = conf[bn * NB_K + k];
  }
  __syncthreads();

  float acc = b1[c];
  for (int i = 0; i < NB_C + 4 * NB_K; ++i) acc += s_ctx[i] * W1[i * 256 + c];
  float h = 0.5f * acc *
            (1.0f + tanhf(0.7978845608028654f * (acc + 0.044715f * acc * acc * acc)));
  for (int j = 0; j < 4; ++j) {
    float2 lj = blk_sum2(h * W2[c * 4 + j], 0.f, sbuf);
    if (c == 0) out_logits[bn * 4 + j] = lj.x + b2[j];
  }

  if (c == 0) {
    bool anyv = false, hasfree = false;
    for (int k = 0; k < NB_K; ++k) {
      if (getValid(valid, vmode, bn * NB_K + k)) anyv = true; else hasfree = true;
    }
    int tgt = 0; float best = s_sim[0];
    for (int k = 1; k < NB_K; ++k) if (s_sim[k] > best) { best = s_sim[k]; tgt = k; }
    if (!anyv) tgt = 0;
    float max_sim = anyv ? s_sim[tgt] : 0.0f;
    int action = 1;                       // REFINE
    if (max_sim > 0.85f) action = 0;      // KEEP
    bool low = max_sim < 0.5f;
    if (low && hasfree) action = 3;       // SPAWN
    if (low && !hasfree) action = 2;      // REPLACE
    int worst = 0; float wb = -1e30f;
    for (int k = 0; k < NB_K; ++k) {
      float sc = age[bn * NB_K + k] - usage[bn * NB_K + k] - conf[bn * NB_K + k] +
                 (getValid(valid, vmode, bn * NB_K + k) ? 0.f : 1000.f);
      if (sc > wb) { wb = sc; worst = k; }
    }
    int freeslot = 0;
    for (int k = 0; k < NB_K; ++k) {
      if (!getValid(valid, vmode, bn * NB_K + k)) { freeslot = k; break; }
    }
    int chosen = tgt;
    if (action == 3) chosen = hasfree ? freeslot : worst;
    if (action == 2) chosen = worst;
    s_dec[0] = chosen;
    s_dec[1] = (action == 1);
    s_dec[2] = (action == 2 || action == 3);
    s_dec[3] = (action != 0);
  }
  __syncthreads();

  // proto_new (unnormalized) + normalized bank -> workspace, layout [c][k]
  int chosen = s_dec[0];
  float oldp = pr[chosen * NB_C + c];
  float t = 0.9f * oldp + 0.1f * s_cand[c];
  float2 tn = blk_sum2(t * t, 0.f, sbuf);
  float invt = 1.0f / fmaxf(sqrtf(tn.x), 1e-12f);
  float pn_chosen = s_dec[1] ? t * invt : (s_dec[2] ? s_cand[c] : oldp);
  float nb_chosen = s_dec[1] ? t * invt
                   : (s_dec[2] ? s_cand[c] : oldp * s_invn[chosen]);
  float* nbp = ws + WS_NB + (size_t)bn * NB_K * NB_C;
  float* pnp = ws + WS_PN + (size_t)bn * NB_K * NB_C;
  for (int k = 0; k < NB_K; ++k) {
    float praw = pr[k * NB_C + c];
    nbp[c * NB_K + k] = (k == chosen) ? nb_chosen : praw * s_invn[k];
    pnp[c * NB_K + k] = (k == chosen) ? pn_chosen : praw;
  }
  if (c < NB_K) {
    bool v = getValid(valid, vmode, bn * NB_K + c) || (c == chosen && s_dec[3]);
    ws[WS_VAL + bn * NB_K + c] = v ? 1.0f : 0.0f;
  }
}

// ---------------- kernel 3a: partial score dots (float4 over px, 4-way c-split) ----
// grid = bn(32) x slab(4) x pxchunk(4) = 512 blocks; thread owns 4 px.
__global__ __launch_bounds__(256) void k3a_scores(
    const float* __restrict__ value, const float* __restrict__ ws_ro,
    float* __restrict__ ws) {
  __shared__ float s_nb[64 * NB_K];  // 4 KB: nb rows for this c-slab
  int blk = blockIdx.x;
  int bn = blk >> 4, slab = (blk >> 2) & 3, pxc = blk & 3;
  int tid = threadIdx.x;
  int p = pxc * 1024 + tid * 4;
  int gpx = bn * NB_P + p;

  // stage nb slab ([c][k] layout -> contiguous 4 KB)
  const float4* nb4 = (const float4*)(ws_ro + WS_NB + (size_t)bn * NB_C * NB_K +
                                      slab * 64 * NB_K);
  ((float4*)s_nb)[tid] = nb4[tid];
  __syncthreads();

  const float* vp = value + ((size_t)bn * NB_C + slab * 64) * NB_P + p;
  float4 d4[NB_K];
#pragma unroll
  for (int k = 0; k < NB_K; ++k) d4[k] = make_float4(0.f, 0.f, 0.f, 0.f);
  float4 ss = make_float4(0.f, 0.f, 0.f, 0.f);
#pragma unroll 4
  for (int c = 0; c < 64; ++c) {
    float4 v = *(const float4*)(vp + (size_t)c * NB_P);
    ss.x += v.x * v.x; ss.y += v.y * v.y; ss.z += v.z * v.z; ss.w += v.w * v.w;
    const float4* nrow = (const float4*)(s_nb + c * NB_K);
    float4 n0 = nrow[0], n1 = nrow[1], n2 = nrow[2], n3 = nrow[3];
#define ACC(K, S)                                                        \
    d4[K].x += v.x * S; d4[K].y += v.y * S; d4[K].z += v.z * S; d4[K].w += v.w * S;
    ACC(0, n0.x)  ACC(1, n0.y)  ACC(2, n0.z)  ACC(3, n0.w)
    ACC(4, n1.x)  ACC(5, n1.y)  ACC(6, n1.z)  ACC(7, n1.w)
    ACC(8, n2.x)  ACC(9, n2.y)  ACC(10, n2.z) ACC(11, n2.w)
    ACC(12, n3.x) ACC(13, n3.y) ACC(14, n3.z) ACC(15, n3.w)
#undef ACC
  }
  float* base = ws + WS_PART + (size_t)slab * 17 * NB_GP;
#pragma unroll
  for (int k = 0; k < NB_K; ++k)
    *(nfloat4*)(base + (size_t)k * NB_GP + gpx) =
        (nfloat4){d4[k].x, d4[k].y, d4[k].z, d4[k].w};
  *(nfloat4*)(base + (size_t)16 * NB_GP + gpx) = (nfloat4){ss.x, ss.y, ss.z, ss.w};
}

// ---------------- kernel 3c: combine partials + softmax -> weights ----------------
// grid = 512 blocks x 256 threads, one pixel per thread.
__global__ __launch_bounds__(256) void k3c_softmax(float* __restrict__ ws) {
  __shared__ int s_vmask;
  int gpx = blockIdx.x * 256 + threadIdx.x;
  int bn = gpx >> 12;
  if (threadIdx.x == 0) {
    int vm = 0;
    for (int k = 0; k < NB_K; ++k)
      if (ws[WS_VAL + bn * NB_K + k] != 0.0f) vm |= (1 << k);
    s_vmask = vm;
  }
  __syncthreads();
  int vmask = s_vmask;

  const float* base = ws + WS_PART;
  float d[NB_K];
  float ssum = 0.f;
#pragma unroll
  for (int k = 0; k < NB_K; ++k) {
    float a = 0.f;
#pragma unroll
    for (int s = 0; s < 4; ++s)
      a += base[(size_t)(s * 17 + k) * NB_GP + gpx];
    d[k] = a;
  }
#pragma unroll
  for (int s = 0; s < 4; ++s) ssum += base[(size_t)(s * 17 + 16) * NB_GP + gpx];

  float invv = 1.0f / fmaxf(sqrtf(ssum), 1e-12f);
  float m = -1e30f;
#pragma unroll
  for (int k = 0; k < NB_K; ++k) {
    d[k] *= invv;
    if ((vmask >> k) & 1) m = fmaxf(m, d[k]);
  }
  float w[NB_K]; float es = 0.f;
#pragma unroll
  for (int k = 0; k < NB_K; ++k) {
    float e = ((vmask >> k) & 1) ? __expf(d[k] - m) : 0.f;
    w[k] = e; es += e;
  }
  float isum = vmask ? (1.0f / es) : 0.0f;
#pragma unroll
  for (int k = 0; k < NB_K; ++k)
    ws[WS_W + (size_t)k * NB_GP + gpx] = w[k] * isum;
}

// ---------------- kernel 3b: apply (float4 over px, c-chunked) ----------------
// grid = bn(32) x cchunk(8) x pxchunk(4) = 1024 blocks; thread owns 4 px.
__global__ __launch_bounds__(256) void k3b_apply(
    const float* __restrict__ value, const float* __restrict__ frame,
    const float* __restrict__ ws, const float* __restrict__ pgp,
    const float* __restrict__ fgp, float* __restrict__ out) {
  __shared__ float s_pn[32 * NB_K];  // 2 KB: pn rows for this c-chunk
  int blk = blockIdx.x;
  int bn = blk >> 5, cc = (blk >> 2) & 7, pxc = blk & 3;
  int b = bn >> 3;
  int tid = threadIdx.x;
  int p = pxc * 1024 + tid * 4;
  int gpx = bn * NB_P + p;

  if (tid < 128) {
    const float4* pn4 = (const float4*)(ws + WS_PN + (size_t)bn * NB_C * NB_K +
                                        cc * 32 * NB_K);
    ((float4*)s_pn)[tid] = pn4[tid];
  }
  float pg = pgp[0], fg = fgp[0];
  // per-thread weights for its 4 px: float4 lanes = px
  float4 w4[NB_K];
#pragma unroll
  for (int k = 0; k < NB_K; ++k)
    w4[k] = *(const float4*)(ws + WS_W + (size_t)k * NB_GP + gpx);
  __syncthreads();

  const float* vp = value + ((size_t)bn * NB_C + cc * 32) * NB_P + p;
  const float* fp = frame + ((size_t)b * NB_C + cc * 32) * NB_P + p;
  float* op = out + ((size_t)bn * NB_C + cc * 32) * NB_P + p;
#pragma unroll 2
  for (int c = 0; c < 32; ++c) {
    float4 v = *(const float4*)(vp + (size_t)c * NB_P);
    float4 f = *(const float4*)(fp + (size_t)c * NB_P);
    const float4* prow = (const float4*)(s_pn + c * NB_K);
    float4 p0 = prow[0], p1 = prow[1], p2 = prow[2], p3 = prow[3];
    float4 pm = make_float4(0.f, 0.f, 0.f, 0.f);
#define APM(K, S)                                                        \
    pm.x += w4[K].x * S; pm.y += w4[K].y * S; pm.z += w4[K].z * S; pm.w += w4[K].w * S;
    APM(0, p0.x)  APM(1, p0.y)  APM(2, p0.z)  APM(3, p0.w)
    APM(4, p1.x)  APM(5, p1.y)  APM(6, p1.z)  APM(7, p1.w)
    APM(8, p2.x)  APM(9, p2.y)  APM(10, p2.z) APM(11, p2.w)
    APM(12, p3.x) APM(13, p3.y) APM(14, p3.z) APM(15, p3.w)
#undef APM
    nfloat4 o;
    o.x = v.x + pg * pm.x + fg * f.x;
    o.y = v.y + pg * pm.y + fg * f.y;
    o.z = v.z + pg * pm.z + fg * f.z;
    o.w = v.w + pg * pm.w + fg * f.w;
    __builtin_nontemporal_store(o, (nfloat4*)(op + (size_t)c * NB_P));
  }
}

// ---------------- fallback fused kernel 3 (small ws) ----------------
__global__ __launch_bounds__(256, 4) void k3_readout(
    const float* __restrict__ value, const float* __restrict__ frame,
    const float* __restrict__ ws, const float* __restrict__ pgp,
    const float* __restrict__ fgp, float* __restrict__ out) {
  __shared__ float s_bank[NB_C * NB_K];
  __shared__ float s_red[256 * 17];
  int blk = blockIdx.x;
  int bn = blk >> 5, tile = blk & 31;
  int b = bn >> 3;
  int tid = threadIdx.x;
  int px = tid & 127, ch = tid >> 7;
  int p0 = tile * 128;

  const float4* nbp4 = (const float4*)(ws + WS_NB + (size_t)bn * NB_K * NB_C);
  float4* sb4 = (float4*)s_bank;
#pragma unroll
  for (int j = 0; j < 4; ++j) sb4[j * 256 + tid] = nbp4[j * 256 + tid];
  int vmask = 0;
  for (int k = 0; k < NB_K; ++k)
    if (ws[WS_VAL + bn * NB_K + k] != 0.0f) vmask |= (1 << k);
  float pg = pgp[0], fg = fgp[0];
  __syncthreads();

  const float* vp = value + ((size_t)bn * NB_C + ch * 128) * NB_P + p0 + px;
  const float* sbch = s_bank + ch * 128 * NB_K;
  float d[NB_K];
#pragma unroll
  for (int k = 0; k < NB_K; ++k) d[k] = 0.f;
  float sumsq = 0.f;
#pragma unroll 8
  for (int c = 0; c < 128; ++c) {
    float v = vp[(size_t)c * NB_P];
    sumsq += v * v;
    const float4* n4 = (const float4*)(sbch + c * NB_K);
    float4 n0 = n4[0], n1 = n4[1], n2 = n4[2], n3 = n4[3];
    d[0] += v * n0.x;  d[1] += v * n0.y;  d[2] += v * n0.z;  d[3] += v * n0.w;
    d[4] += v * n1.x;  d[5] += v * n1.y;  d[6] += v * n1.z;  d[7] += v * n1.w;
    d[8] += v * n2.x;  d[9] += v * n2.y;  d[10] += v * n2.z; d[11] += v * n2.w;
    d[12] += v * n3.x; d[13] += v * n3.y; d[14] += v * n3.z; d[15] += v * n3.w;
  }
  {
    float* rr = s_red + tid * 17;
#pragma unroll
    for (int k = 0; k < NB_K; ++k) rr[k] = d[k];
    rr[16] = sumsq;
  }
  __syncthreads();
  const float4* pnp4 = (const float4*)(ws + WS_PN + (size_t)bn * NB_K * NB_C);
#pragma unroll
  for (int j = 0; j < 4; ++j) sb4[j * 256 + tid] = pnp4[j * 256 + tid];
  {
    const float* r0 = s_red + px * 17;
    const float* r1 = s_red + (128 + px) * 17;
#pragma unroll
    for (int k = 0; k < NB_K; ++k) d[k] = r0[k] + r1[k];
    sumsq = r0[16] + r1[16];
  }
  float invv = 1.0f / fmaxf(sqrtf(sumsq), 1e-12f);
  float m = -1e30f;
#pragma unroll
  for (int k = 0; k < NB_K; ++k) {
    d[k] *= invv;
    if ((vmask >> k) & 1) m = fmaxf(m, d[k]);
  }
  float w[NB_K]; float ssum = 0.f;
#pragma unroll
  for (int k = 0; k < NB_K; ++k) {
    float e = ((vmask >> k) & 1) ? __expf(d[k] - m) : 0.f;
    w[k] = e; ssum += e;
  }
  float isum = vmask ? (1.0f / ssum) : 0.0f;
#pragma unroll
  for (int k = 0; k < NB_K; ++k) w[k] *= isum;
  __syncthreads();

  const float* fp = frame + ((size_t)b * NB_C + ch * 128) * NB_P + p0 + px;
  float* op = out + ((size_t)bn * NB_C + ch * 128) * NB_P + p0 + px;
#pragma unroll 4
  for (int c = 0; c < 128; ++c) {
    float v = vp[(size_t)c * NB_P];
    float f = fp[(size_t)c * NB_P];
    const float4* n4 = (const float4*)(sbch + c * NB_K);
    float4 n0 = n4[0], n1 = n4[1], n2 = n4[2], n3 = n4[3];
    float pm = w[0] * n0.x + w[1] * n0.y + w[2] * n0.z + w[3] * n0.w +
               w[4] * n1.x + w[5] * n1.y + w[6] * n1.z + w[7] * n1.w +
               w[8] * n2.x + w[9] * n2.y + w[10] * n2.z + w[11] * n2.w +
               w[12] * n3.x + w[13] * n3.y + w[14] * n3.z + w[15] * n3.w;
    __builtin_nontemporal_store(v + pg * pm + fg * f, &op[(size_t)c * NB_P]);
  }
}

extern "C" void kernel_launch(void* const* d_in, const int* in_sizes, int n_in,
                              void* d_out, int out_size, void* d_ws, size_t ws_size,
                              hipStream_t stream) {
  const float* value = (const float*)d_in[0];
  const float* frame = (const float*)d_in[1];
  const float* mask  = (const float*)d_in[2];
  const float* proto = (const float*)d_in[3];
  const float* age   = (const float*)d_in[4];
  const float* usage = (const float*)d_in[5];
  const float* conf  = (const float*)d_in[6];
  const void*  valid = (const void*)d_in[7];
  const float* W1 = (const float*)d_in[8];
  const float* b1 = (const float*)d_in[9];
  const float* W2 = (const float*)d_in[10];
  const float* b2 = (const float*)d_in[11];
  const float* pg = (const float*)d_in[12];
  const float* fg = (const float*)d_in[13];
  float* out = (float*)d_out;
  float* ws = (float*)d_ws;

  int g1 = NB_BN * NB_C + NB_B * NB_C + NB_BN;  // 9248
  hipLaunchKernelGGL(k1_reduce, dim3(g1), dim3(256), 0, stream,
                     value, frame, mask, ws);
  hipLaunchKernelGGL(k2_policy, dim3(NB_BN), dim3(256), 0, stream,
                     proto, age, usage, conf, valid, W1, b1, W2, b2, ws,
                     out + (size_t)NB_BN * NB_C * NB_P);
  if (ws_size >= (size_t)WS_END * sizeof(float)) {
    hipLaunchKernelGGL(k3a_scores, dim3(512), dim3(256), 0, stream,
                       value, ws, ws);
    hipLaunchKernelGGL(k3c_softmax, dim3(512), dim3(256), 0, stream, ws);
    hipLaunchKernelGGL(k3b_apply, dim3(1024), dim3(256), 0, stream,
                       value, frame, ws, pg, fg, out);
  } else {
    hipLaunchKernelGGL(k3_readout, dim3(NB_BN * 32), dim3(256), 0, stream,
                       value, frame, ws, pg, fg, out);
  }
}